// Round 13
// baseline (95.059 us; speedup 1.0000x reference)
//
#include <hip/hip_runtime.h>
#include <hip/hip_bf16.h>

#define EPSV 1e-5f

typedef __attribute__((ext_vector_type(8))) short short8v;
typedef __attribute__((ext_vector_type(4))) short short4v;
typedef __attribute__((ext_vector_type(4))) float float4v;

__device__ inline unsigned short f2bf(float x) {
  __hip_bfloat16 h = __float2bfloat16(x);   // RNE
  return *reinterpret_cast<unsigned short*>(&h);
}
__device__ inline float bf2f(unsigned short b) {
  unsigned u = ((unsigned)b) << 16;
  float f;
  __builtin_memcpy(&f, &u, 4);
  return f;
}

// ---- window-sum compute from a wave-private LDS span -----------------------
template <int L, int MAXW, int OPL>
__device__ __forceinline__ void windows_from_seg(
    const float* __restrict__ seg, int lbase, float wst,
    unsigned short* __restrict__ outp, int lane) {
  int sbase = (lbase * L) >> 8;              // exact at span boundaries
  unsigned short res[OPL];
  #pragma unroll
  for (int oo = 0; oo < OPL; ++oo) {
    int l = lbase + lane * OPL + oo;
    int start = ((l * L) >> 8) - sbase;
    int end = (((l + 1) * L + 255) >> 8) - sbase;
    int width = end - start;
    float s = 0.f;
    #pragma unroll
    for (int i = 0; i < MAXW; ++i) {
      float v = seg[start + i];
      s += (i < width) ? v : 0.f;
    }
    res[oo] = f2bf(s / (float)width * wst);
  }
  if (OPL == 2) {
    unsigned pk = ((unsigned)res[1] << 16) | res[0];
    *(unsigned*)(outp + lane * 2) = pk;
  } else {
    unsigned pk0 = ((unsigned)res[1] << 16) | res[0];
    unsigned pk1 = ((unsigned)res[3] << 16) | res[2];
    unsigned long long pk = ((unsigned long long)pk1 << 32) | pk0;
    *(unsigned long long*)(outp + lane * 4) = pk;
  }
}

// ---- two-span per-wave pipeline: B's HBM latency hides under A's compute ---
template <int L, int SPAN, int MAXW, int OPL>
__device__ __forceinline__ void pool_span2_vec(
    const float* __restrict__ pA, const float* __restrict__ pB,
    int lbA, int lbB, float wst,
    unsigned short* __restrict__ outA, unsigned short* __restrict__ outB,
    float* __restrict__ seg, int lane) {
  constexpr int S4 = SPAN / 4;
  constexpr int NLD = (S4 + 63) / 64;
  float4v rA[NLD], rB[NLD];
  const float4v* gA = (const float4v*)pA;
  const float4v* gB = (const float4v*)pB;
  #pragma unroll
  for (int j = 0; j < NLD; ++j) {            // issue span A (10 in flight)
    int idx = lane + 64 * j;
    if (NLD * 64 == S4 || idx < S4) rA[j] = __builtin_nontemporal_load(gA + idx);
  }
  #pragma unroll
  for (int j = 0; j < NLD; ++j) {            // issue span B (20 in flight)
    int idx = lane + 64 * j;
    if (NLD * 64 == S4 || idx < S4) rB[j] = __builtin_nontemporal_load(gB + idx);
  }
  if (lane < MAXW + 3) seg[SPAN + lane] = 0.f;   // zero pad (valid for both)
  #pragma unroll
  for (int j = 0; j < NLD; ++j) {            // write A (waits vmcnt(10) only)
    int idx = lane + 64 * j;
    if (NLD * 64 == S4 || idx < S4) *(float4v*)&seg[idx * 4] = rA[j];
  }
  windows_from_seg<L, MAXW, OPL>(seg, lbA, wst, outA, lane);
  #pragma unroll
  for (int j = 0; j < NLD; ++j) {            // write B (same-wave DS order: safe)
    int idx = lane + 64 * j;
    if (NLD * 64 == S4 || idx < S4) *(float4v*)&seg[idx * 4] = rB[j];
  }
  windows_from_seg<L, MAXW, OPL>(seg, lbB, wst, outB, lane);
}

// ---- stage3: single-span scalar (rows only 4B-aligned; 2.4% of traffic) ----
template <int L, int SPAN, int MAXW, int OPL>
__device__ __forceinline__ void pool_span_scalar(
    const float* __restrict__ spanp, int lbase, float wst,
    unsigned short* __restrict__ outp, float* __restrict__ seg, int lane) {
  constexpr int NLD = (SPAN + 63) / 64;
  if (lane < MAXW + 3) seg[SPAN + lane] = 0.f;
  #pragma unroll
  for (int j = 0; j < NLD; ++j) {
    int idx = lane + 64 * j;
    if (idx < SPAN) seg[idx] = __builtin_nontemporal_load(spanp + idx);
  }
  windows_from_seg<L, MAXW, OPL>(seg, lbase, wst, outp, lane);
}

// ------------- Kernel 1: barrier-free wave-private pool + quant tail --------
// 4 waves/block, each wave independent in its 2524-float LDS segment.
// stage1 [0,4096): wave = row rr (both halves, pipelined)
// stage2 [4096,5120): wave = 2 rows (pipelined)
// stage3 [5120,6144): wave = 1 row
// quant  [6144,6272)
__global__ __launch_bounds__(256) void pool_quant_kernel(
    const float* __restrict__ s1, const float* __restrict__ s2,
    const float* __restrict__ s3, const float* __restrict__ alpha,
    const float* __restrict__ w, unsigned short* __restrict__ fusedb,
    unsigned short* __restrict__ qbf, float* __restrict__ scales) {
  __shared__ float pool_lds[4][2524];   // 40,384 B -> 4 blocks/CU
  int bid = blockIdx.x;
  int t = threadIdx.x;
  int wv = t >> 6, lane = t & 63;

  if (bid >= 6144) {                // ---- quant tail ----
    int o = bid - 6144;             // 0..127
    const float* wr = w + o * 448;
    float m = 0.f;
    for (int c = t; c < 448; c += 256) m = fmaxf(m, fabsf(wr[c]));
    float* sm = pool_lds[0];        // reuse LDS
    for (int off = 32; off; off >>= 1) m = fmaxf(m, __shfl_down(m, off, 64));
    if ((t & 63) == 0) sm[t >> 6] = m;
    __syncthreads();
    m = fmaxf(fmaxf(sm[0], sm[1]), fmaxf(sm[2], sm[3]));
    float scale = fmaxf(m, 1e-8f);  // qp = 1 for 2-bit symmetric
    for (int c = t; c < 448; c += 256) {
      float q = rintf(wr[c] / scale);      // RNE == jnp.round
      q = fminf(fmaxf(q, -2.f), 1.f);
      qbf[o * 448 + c] = f2bf(q);          // q in {-2,-1,0,1}: exact bf16
    }
    if (t == 0) scales[o] = scale;
    return;
  }

  float a0 = alpha[0], a1 = alpha[1], a2 = alpha[2];
  float mx = fmaxf(a0, fmaxf(a1, a2));
  float e0 = expf(a0 - mx), e1 = expf(a1 - mx), e2 = expf(a2 - mx);
  float esum = e0 + e1 + e2;
  float* seg = pool_lds[wv];

  if (bid < 4096) {
    // ---- stage1: L=5000; wave = row rr, halves A/B pipelined ----
    int rr = bid * 4 + wv;          // 0..16383
    int b = rr >> 8, c = rr & 255;
    const float* rowp = s1 + ((size_t)b * 256 + c) * 5000;
    unsigned short* outp = fusedb + ((size_t)b * 448 + c) * 256;
    pool_span2_vec<5000, 2500, 21, 2>(rowp, rowp + 2500, 0, 128, e0 / esum,
                                      outp, outp + 128, seg, lane);
  } else if (bid < 5120) {
    // ---- stage2: L=2500; wave = rows 2w, 2w+1 pipelined ----
    int wt = (bid - 4096) * 4 + wv; // 0..4095
    int rA = wt * 2, rB = rA + 1;   // 0..8191
    int bA = rA >> 7, cA = rA & 127;
    int bB = rB >> 7, cB = rB & 127;
    const float* pA = s2 + ((size_t)bA * 128 + cA) * 2500;
    const float* pB = s2 + ((size_t)bB * 128 + cB) * 2500;
    unsigned short* oA = fusedb + ((size_t)bA * 448 + 256 + cA) * 256;
    unsigned short* oB = fusedb + ((size_t)bB * 448 + 256 + cB) * 256;
    pool_span2_vec<2500, 2500, 11, 4>(pA, pB, 0, 0, e1 / esum, oA, oB, seg, lane);
  } else {
    // ---- stage3: L=625; wave = 1 row ----
    int u = (bid - 5120) * 4 + wv;  // 0..4095
    int b = u >> 6, c = u & 63;
    const float* spanp = s3 + ((size_t)b * 64 + c) * 625;
    unsigned short* outp = fusedb + ((size_t)b * 448 + 384 + c) * 256;
    pool_span_scalar<625, 625, 4, 4>(spanp, 0, e2 / esum, outp, seg, lane);
  }
}

// ------------- Kernel 2: MFMA GEMM -> bf16 y + BN partials ------------------
__global__ __launch_bounds__(256) void mfma_gemm_kernel(
    const unsigned short* __restrict__ qbf, const float* __restrict__ scales,
    const unsigned short* __restrict__ fusedb, const float* __restrict__ bias,
    unsigned short* __restrict__ ybf, float* __restrict__ Psum,
    float* __restrict__ Pssq) {
  __shared__ __align__(16) unsigned short Asm[64][40];
  __shared__ __align__(16) unsigned Bsm32[16][66];   // [k-pair 0..15][n 0..63]
  int b = blockIdx.z;
  int o0 = blockIdx.y * 64;
  int l0 = blockIdx.x * 64;
  int tid = threadIdx.x;
  int wave = tid >> 6, lane = tid & 63;
  int wm = wave >> 1, wn = wave & 1;
  int lrow = lane & 15, lg = lane >> 4;
  const unsigned short* Fp = fusedb + (size_t)b * 448 * 256;
  float4v acc[2][2];
  #pragma unroll
  for (int i = 0; i < 2; ++i)
    #pragma unroll
    for (int j = 0; j < 2; ++j) acc[i][j] = (float4v){0.f, 0.f, 0.f, 0.f};
  for (int c0 = 0; c0 < 448; c0 += 32) {
    { int r = tid >> 2, k0 = (tid & 3) * 8;
      *(short8v*)&Asm[r][k0] = *(const short8v*)(qbf + (size_t)(o0 + r) * 448 + c0 + k0); }
    { int kp = tid >> 4, n0 = (tid & 15) * 4;
      const unsigned short* g0 = Fp + (size_t)(c0 + 2 * kp) * 256 + l0 + n0;
      short4v v0 = *(const short4v*)g0;
      short4v v1 = *(const short4v*)(g0 + 256);
      #pragma unroll
      for (int j = 0; j < 4; ++j)
        Bsm32[kp][n0 + j] =
            (((unsigned)(unsigned short)v1[j]) << 16) | (unsigned short)v0[j];
    }
    __syncthreads();
    short8v af[2];
    #pragma unroll
    for (int mf = 0; mf < 2; ++mf)
      af[mf] = *(const short8v*)&Asm[wm * 32 + mf * 16 + lrow][lg * 8];
    #pragma unroll
    for (int nf = 0; nf < 2; ++nf) {
      int n = wn * 32 + nf * 16 + lrow;
      int tmp[4];
      #pragma unroll
      for (int jj = 0; jj < 4; ++jj) tmp[jj] = (int)Bsm32[lg * 4 + jj][n];
      short8v bf;
      __builtin_memcpy(&bf, tmp, 16);
      #pragma unroll
      for (int mf = 0; mf < 2; ++mf)
        acc[mf][nf] = __builtin_amdgcn_mfma_f32_16x16x32_bf16(af[mf], bf, acc[mf][nf], 0, 0, 0);
    }
    __syncthreads();
  }
  float sv[2][4], qv[2][4];
  #pragma unroll
  for (int mf = 0; mf < 2; ++mf) {
    #pragma unroll
    for (int reg = 0; reg < 4; ++reg) {
      int r = o0 + wm * 32 + mf * 16 + lg * 4 + reg;
      float sc = scales[r], bv = bias[r];
      float s = 0.f, q = 0.f;
      #pragma unroll
      for (int nf = 0; nf < 2; ++nf) {
        int col = l0 + wn * 32 + nf * 16 + lrow;
        float val = acc[mf][nf][reg] * sc + bv;
        ybf[((size_t)b * 128 + r) * 256 + col] = f2bf(val);
        s += val; q += val * val;              // partials from f32 (pre-round)
      }
      sv[mf][reg] = s; qv[mf][reg] = q;
    }
  }
  #pragma unroll
  for (int mf = 0; mf < 2; ++mf)
    #pragma unroll
    for (int reg = 0; reg < 4; ++reg)
      #pragma unroll
      for (int m = 1; m < 16; m <<= 1) {
        sv[mf][reg] += __shfl_xor(sv[mf][reg], m, 64);
        qv[mf][reg] += __shfl_xor(qv[mf][reg], m, 64);
      }
  if (lrow == 0) {
    int slot = b * 8 + blockIdx.x * 2 + wn;   // 0..511 fixed slot
    #pragma unroll
    for (int mf = 0; mf < 2; ++mf)
      #pragma unroll
      for (int reg = 0; reg < 4; ++reg) {
        int r = o0 + wm * 32 + mf * 16 + lg * 4 + reg;
        Psum[r * 512 + slot] = sv[mf][reg];
        Pssq[r * 512 + slot] = qv[mf][reg];
      }
  }
}

// ------------- Kernel 3: inline stats + BN + ELU + mean over L --------------
__global__ __launch_bounds__(256) void final_kernel(
    const unsigned short* __restrict__ ybf, const float* __restrict__ Psum,
    const float* __restrict__ Pssq, const float* __restrict__ gamma,
    const float* __restrict__ beta, float* __restrict__ out) {
  int w = threadIdx.x >> 6;
  int lane = threadIdx.x & 63;
  int bo = blockIdx.x * 4 + w;     // b*128 + o
  int o = bo & 127;

  float s = 0.f, q = 0.f;
  const float* Pp = Psum + o * 512 + lane * 8;
  const float* Qp = Pssq + o * 512 + lane * 8;
  #pragma unroll
  for (int i = 0; i < 8; ++i) { s += Pp[i]; q += Qp[i]; }
  #pragma unroll
  for (int m = 1; m < 64; m <<= 1) {
    s += __shfl_xor(s, m, 64);
    q += __shfl_xor(q, m, 64);
  }
  float mean = s * (1.f / 16384.f);
  float var = q * (1.f / 16384.f) - mean * mean;
  float rs = rsqrtf(var + EPSV);
  float a = rs * gamma[o];
  float bb = beta[o] - mean * a;

  ushort4 v = *(const ushort4*)(ybf + (size_t)bo * 256 + lane * 4);
  float acc = 0.f;
  #pragma unroll
  for (int j = 0; j < 4; ++j) {
    float e = bf2f((&v.x)[j]);
    float yn = e * a + bb;
    acc += yn > 0.f ? yn : expm1f(yn);
  }
  for (int m = 32; m; m >>= 1) acc += __shfl_down(acc, m, 64);
  if (lane == 0) out[bo] = acc * (1.f / 256.f);
}

extern "C" void kernel_launch(void* const* d_in, const int* in_sizes, int n_in,
                              void* d_out, int out_size, void* d_ws, size_t ws_size,
                              hipStream_t stream) {
  const float* s1     = (const float*)d_in[0];
  const float* s2     = (const float*)d_in[1];
  const float* s3     = (const float*)d_in[2];
  const float* alpha  = (const float*)d_in[3];
  const float* weight = (const float*)d_in[4];
  const float* bias   = (const float*)d_in[5];
  const float* gamma  = (const float*)d_in[6];
  const float* beta   = (const float*)d_in[7];
  float* out = (float*)d_out;

  char* ws = (char*)d_ws;
  unsigned short* fusedb = (unsigned short*)ws;              // 14,680,064
  unsigned short* qbf    = (unsigned short*)(ws + 14680064); //    114,688
  float* scales          = (float*)(ws + 14794752);          //        512
  unsigned short* ybf    = (unsigned short*)(ws + 14795264); //  4,194,304
  float* Psum            = (float*)(ws + 18989568);          //    262,144
  float* Pssq            = (float*)(ws + 19251712);          //    262,144

  pool_quant_kernel<<<6272, 256, 0, stream>>>(s1, s2, s3, alpha, weight,
                                              fusedb, qbf, scales);
  dim3 g(4, 2, 64);
  mfma_gemm_kernel<<<g, 256, 0, stream>>>(qbf, scales, fusedb, bias, ybf,
                                          Psum, Pssq);
  final_kernel<<<2048, 256, 0, stream>>>(ybf, Psum, Pssq, gamma, beta, out);
}

// Round 14
// 95.000 us; speedup vs baseline: 1.0006x; 1.0006x over previous
//
#include <hip/hip_runtime.h>
#include <hip/hip_bf16.h>

#define EPSV 1e-5f

typedef __attribute__((ext_vector_type(8))) short short8v;
typedef __attribute__((ext_vector_type(4))) short short4v;
typedef __attribute__((ext_vector_type(4))) float float4v;
typedef __attribute__((ext_vector_type(2))) float float2v;

__device__ inline unsigned short f2bf(float x) {
  __hip_bfloat16 h = __float2bfloat16(x);   // RNE
  return *reinterpret_cast<unsigned short*>(&h);
}
__device__ inline float bf2f(unsigned short b) {
  unsigned u = ((unsigned)b) << 16;
  float f;
  __builtin_memcpy(&f, &u, 4);
  return f;
}

// ---- window-sum compute from a wave-private LDS span -----------------------
template <int L, int MAXW, int OPL>
__device__ __forceinline__ void windows_from_seg(
    const float* __restrict__ seg, int lbase, float wst,
    unsigned short* __restrict__ outp, int lane) {
  int sbase = (lbase * L) >> 8;              // exact at span boundaries
  unsigned short res[OPL];
  #pragma unroll
  for (int oo = 0; oo < OPL; ++oo) {
    int l = lbase + lane * OPL + oo;
    int start = ((l * L) >> 8) - sbase;
    int end = (((l + 1) * L + 255) >> 8) - sbase;
    int width = end - start;
    float s = 0.f;
    #pragma unroll
    for (int i = 0; i < MAXW; ++i) {
      float v = seg[start + i];
      s += (i < width) ? v : 0.f;
    }
    res[oo] = f2bf(s / (float)width * wst);
  }
  if (OPL == 1) {
    outp[lane] = res[0];
  } else if (OPL == 2) {
    unsigned pk = ((unsigned)res[1] << 16) | res[0];
    *(unsigned*)(outp + lane * 2) = pk;
  } else {
    unsigned pk0 = ((unsigned)res[1] << 16) | res[0];
    unsigned pk1 = ((unsigned)res[3] << 16) | res[2];
    unsigned long long pk = ((unsigned long long)pk1 << 32) | pk0;
    *(unsigned long long*)(outp + lane * 4) = pk;
  }
}

// ---- one wave-private span: load (VECW-wide) -> LDS -> window sums ---------
template <int L, int SPAN, int MAXW, int OPL, int VECW>
__device__ __forceinline__ void pool_span(
    const float* __restrict__ spanp, int lbase, float wst,
    unsigned short* __restrict__ outp, float* __restrict__ seg, int lane) {
  if (lane < MAXW) seg[SPAN + lane] = 0.f;   // zero pad for masked reads
  if (VECW == 4) {
    constexpr int SV = SPAN / 4;
    constexpr int NLD = (SV + 63) / 64;
    const float4v* gp = (const float4v*)spanp;
    #pragma unroll
    for (int j = 0; j < NLD; ++j) {
      int idx = lane + 64 * j;
      if (NLD * 64 == SV || idx < SV) {
        float4v v = __builtin_nontemporal_load(gp + idx);
        *(float4v*)&seg[idx * 4] = v;
      }
    }
  } else if (VECW == 2) {
    constexpr int SV = SPAN / 2;
    constexpr int NLD = (SV + 63) / 64;
    const float2v* gp = (const float2v*)spanp;
    #pragma unroll
    for (int j = 0; j < NLD; ++j) {
      int idx = lane + 64 * j;
      if (NLD * 64 == SV || idx < SV) {
        float2v v = __builtin_nontemporal_load(gp + idx);
        *(float2v*)&seg[idx * 2] = v;
      }
    }
  } else {
    constexpr int NLD = (SPAN + 63) / 64;
    #pragma unroll
    for (int j = 0; j < NLD; ++j) {
      int idx = lane + 64 * j;
      if (idx < SPAN) seg[idx] = __builtin_nontemporal_load(spanp + idx);
    }
  }
  windows_from_seg<L, MAXW, OPL>(seg, lbase, wst, outp, lane);
}

// ------------- Kernel 1: barrier-free wave-private pool + quant tail --------
// 4 waves/block, each independent in a 1280-float LDS segment (20.0 KB/block
// -> 8 blocks/CU, 32 waves/CU at <=64 VGPR).
// stage1 [0,16384): wave = quarter-row (1250 f, 64 outs)
// stage2 [16384,20480): wave = half-row (1250 f, 128 outs)
// stage3 [20480,21504): wave = full row (625 f, 256 outs)
// quant  [21504,21632)
__global__ __launch_bounds__(256, 8) void pool_quant_kernel(
    const float* __restrict__ s1, const float* __restrict__ s2,
    const float* __restrict__ s3, const float* __restrict__ alpha,
    const float* __restrict__ w, unsigned short* __restrict__ fusedb,
    unsigned short* __restrict__ qbf, float* __restrict__ scales) {
  __shared__ float pool_lds[4][1280];   // 20,480 B -> 8 blocks/CU
  int bid = blockIdx.x;
  int t = threadIdx.x;
  int wv = t >> 6, lane = t & 63;

  if (bid >= 21504) {               // ---- quant tail ----
    int o = bid - 21504;            // 0..127
    const float* wr = w + o * 448;
    float m = 0.f;
    for (int c = t; c < 448; c += 256) m = fmaxf(m, fabsf(wr[c]));
    float* sm = pool_lds[0];        // reuse LDS
    for (int off = 32; off; off >>= 1) m = fmaxf(m, __shfl_down(m, off, 64));
    if ((t & 63) == 0) sm[t >> 6] = m;
    __syncthreads();
    m = fmaxf(fmaxf(sm[0], sm[1]), fmaxf(sm[2], sm[3]));
    float scale = fmaxf(m, 1e-8f);  // qp = 1 for 2-bit symmetric
    for (int c = t; c < 448; c += 256) {
      float q = rintf(wr[c] / scale);      // RNE == jnp.round
      q = fminf(fmaxf(q, -2.f), 1.f);
      qbf[o * 448 + c] = f2bf(q);          // q in {-2,-1,0,1}: exact bf16
    }
    if (t == 0) scales[o] = scale;
    return;
  }

  float a0 = alpha[0], a1 = alpha[1], a2 = alpha[2];
  float mx = fmaxf(a0, fmaxf(a1, a2));
  float e0 = expf(a0 - mx), e1 = expf(a1 - mx), e2 = expf(a2 - mx);
  float esum = e0 + e1 + e2;
  float* seg = pool_lds[wv];

  if (bid < 16384) {
    // ---- stage1: L=5000; wave = quarter wv of row bid ----
    int b = bid >> 8, c = bid & 255;
    const float* rowp = s1 + ((size_t)b * 256 + c) * 5000;
    unsigned short* outr = fusedb + ((size_t)b * 448 + c) * 256;
    const float* spanp = rowp + wv * 1250;       // even wv: 16B, odd wv: 8B
    unsigned short* outp = outr + wv * 64;
    int lbase = wv * 64;
    if (wv & 1)
      pool_span<5000, 1250, 21, 1, 2>(spanp, lbase, e0 / esum, outp, seg, lane);
    else
      pool_span<5000, 1250, 21, 1, 4>(spanp, lbase, e0 / esum, outp, seg, lane);
  } else if (bid < 20480) {
    // ---- stage2: L=2500; wave = half (wv&1) of row (2*bid' + wv>>1) ----
    int r = (bid - 16384) * 2 + (wv >> 1);       // 0..8191
    int h = wv & 1;
    int b = r >> 7, c = r & 127;
    const float* spanp = s2 + ((size_t)b * 128 + c) * 2500 + h * 1250;
    unsigned short* outp = fusedb + ((size_t)b * 448 + 256 + c) * 256 + h * 128;
    int lbase = h * 128;
    if (h)
      pool_span<2500, 1250, 11, 2, 2>(spanp, lbase, e1 / esum, outp, seg, lane);
    else
      pool_span<2500, 1250, 11, 2, 4>(spanp, lbase, e1 / esum, outp, seg, lane);
  } else {
    // ---- stage3: L=625; wave = full row ----
    int u = (bid - 20480) * 4 + wv;              // 0..4095
    int b = u >> 6, c = u & 63;
    const float* spanp = s3 + ((size_t)b * 64 + c) * 625;
    unsigned short* outp = fusedb + ((size_t)b * 448 + 384 + c) * 256;
    pool_span<625, 625, 4, 4, 1>(spanp, 0, e2 / esum, outp, seg, lane);
  }
}

// ------------- Kernel 2: MFMA GEMM -> bf16 y + BN partials ------------------
__global__ __launch_bounds__(256) void mfma_gemm_kernel(
    const unsigned short* __restrict__ qbf, const float* __restrict__ scales,
    const unsigned short* __restrict__ fusedb, const float* __restrict__ bias,
    unsigned short* __restrict__ ybf, float* __restrict__ Psum,
    float* __restrict__ Pssq) {
  __shared__ __align__(16) unsigned short Asm[64][40];
  __shared__ __align__(16) unsigned Bsm32[16][66];   // [k-pair 0..15][n 0..63]
  int b = blockIdx.z;
  int o0 = blockIdx.y * 64;
  int l0 = blockIdx.x * 64;
  int tid = threadIdx.x;
  int wave = tid >> 6, lane = tid & 63;
  int wm = wave >> 1, wn = wave & 1;
  int lrow = lane & 15, lg = lane >> 4;
  const unsigned short* Fp = fusedb + (size_t)b * 448 * 256;
  float4v acc[2][2];
  #pragma unroll
  for (int i = 0; i < 2; ++i)
    #pragma unroll
    for (int j = 0; j < 2; ++j) acc[i][j] = (float4v){0.f, 0.f, 0.f, 0.f};
  for (int c0 = 0; c0 < 448; c0 += 32) {
    { int r = tid >> 2, k0 = (tid & 3) * 8;
      *(short8v*)&Asm[r][k0] = *(const short8v*)(qbf + (size_t)(o0 + r) * 448 + c0 + k0); }
    { int kp = tid >> 4, n0 = (tid & 15) * 4;
      const unsigned short* g0 = Fp + (size_t)(c0 + 2 * kp) * 256 + l0 + n0;
      short4v v0 = *(const short4v*)g0;
      short4v v1 = *(const short4v*)(g0 + 256);
      #pragma unroll
      for (int j = 0; j < 4; ++j)
        Bsm32[kp][n0 + j] =
            (((unsigned)(unsigned short)v1[j]) << 16) | (unsigned short)v0[j];
    }
    __syncthreads();
    short8v af[2];
    #pragma unroll
    for (int mf = 0; mf < 2; ++mf)
      af[mf] = *(const short8v*)&Asm[wm * 32 + mf * 16 + lrow][lg * 8];
    #pragma unroll
    for (int nf = 0; nf < 2; ++nf) {
      int n = wn * 32 + nf * 16 + lrow;
      int tmp[4];
      #pragma unroll
      for (int jj = 0; jj < 4; ++jj) tmp[jj] = (int)Bsm32[lg * 4 + jj][n];
      short8v bf;
      __builtin_memcpy(&bf, tmp, 16);
      #pragma unroll
      for (int mf = 0; mf < 2; ++mf)
        acc[mf][nf] = __builtin_amdgcn_mfma_f32_16x16x32_bf16(af[mf], bf, acc[mf][nf], 0, 0, 0);
    }
    __syncthreads();
  }
  float sv[2][4], qv[2][4];
  #pragma unroll
  for (int mf = 0; mf < 2; ++mf) {
    #pragma unroll
    for (int reg = 0; reg < 4; ++reg) {
      int r = o0 + wm * 32 + mf * 16 + lg * 4 + reg;
      float sc = scales[r], bv = bias[r];
      float s = 0.f, q = 0.f;
      #pragma unroll
      for (int nf = 0; nf < 2; ++nf) {
        int col = l0 + wn * 32 + nf * 16 + lrow;
        float val = acc[mf][nf][reg] * sc + bv;
        ybf[((size_t)b * 128 + r) * 256 + col] = f2bf(val);
        s += val; q += val * val;              // partials from f32 (pre-round)
      }
      sv[mf][reg] = s; qv[mf][reg] = q;
    }
  }
  #pragma unroll
  for (int mf = 0; mf < 2; ++mf)
    #pragma unroll
    for (int reg = 0; reg < 4; ++reg)
      #pragma unroll
      for (int m = 1; m < 16; m <<= 1) {
        sv[mf][reg] += __shfl_xor(sv[mf][reg], m, 64);
        qv[mf][reg] += __shfl_xor(qv[mf][reg], m, 64);
      }
  if (lrow == 0) {
    int slot = b * 8 + blockIdx.x * 2 + wn;   // 0..511 fixed slot
    #pragma unroll
    for (int mf = 0; mf < 2; ++mf)
      #pragma unroll
      for (int reg = 0; reg < 4; ++reg) {
        int r = o0 + wm * 32 + mf * 16 + lg * 4 + reg;
        Psum[r * 512 + slot] = sv[mf][reg];
        Pssq[r * 512 + slot] = qv[mf][reg];
      }
  }
}

// ------------- Kernel 3: inline stats + BN + ELU + mean over L --------------
__global__ __launch_bounds__(256) void final_kernel(
    const unsigned short* __restrict__ ybf, const float* __restrict__ Psum,
    const float* __restrict__ Pssq, const float* __restrict__ gamma,
    const float* __restrict__ beta, float* __restrict__ out) {
  int w = threadIdx.x >> 6;
  int lane = threadIdx.x & 63;
  int bo = blockIdx.x * 4 + w;     // b*128 + o
  int o = bo & 127;

  float s = 0.f, q = 0.f;
  const float* Pp = Psum + o * 512 + lane * 8;
  const float* Qp = Pssq + o * 512 + lane * 8;
  #pragma unroll
  for (int i = 0; i < 8; ++i) { s += Pp[i]; q += Qp[i]; }
  #pragma unroll
  for (int m = 1; m < 64; m <<= 1) {
    s += __shfl_xor(s, m, 64);
    q += __shfl_xor(q, m, 64);
  }
  float mean = s * (1.f / 16384.f);
  float var = q * (1.f / 16384.f) - mean * mean;
  float rs = rsqrtf(var + EPSV);
  float a = rs * gamma[o];
  float bb = beta[o] - mean * a;

  ushort4 v = *(const ushort4*)(ybf + (size_t)bo * 256 + lane * 4);
  float acc = 0.f;
  #pragma unroll
  for (int j = 0; j < 4; ++j) {
    float e = bf2f((&v.x)[j]);
    float yn = e * a + bb;
    acc += yn > 0.f ? yn : expm1f(yn);
  }
  for (int m = 32; m; m >>= 1) acc += __shfl_down(acc, m, 64);
  if (lane == 0) out[bo] = acc * (1.f / 256.f);
}

extern "C" void kernel_launch(void* const* d_in, const int* in_sizes, int n_in,
                              void* d_out, int out_size, void* d_ws, size_t ws_size,
                              hipStream_t stream) {
  const float* s1     = (const float*)d_in[0];
  const float* s2     = (const float*)d_in[1];
  const float* s3     = (const float*)d_in[2];
  const float* alpha  = (const float*)d_in[3];
  const float* weight = (const float*)d_in[4];
  const float* bias   = (const float*)d_in[5];
  const float* gamma  = (const float*)d_in[6];
  const float* beta   = (const float*)d_in[7];
  float* out = (float*)d_out;

  char* ws = (char*)d_ws;
  unsigned short* fusedb = (unsigned short*)ws;              // 14,680,064
  unsigned short* qbf    = (unsigned short*)(ws + 14680064); //    114,688
  float* scales          = (float*)(ws + 14794752);          //        512
  unsigned short* ybf    = (unsigned short*)(ws + 14795264); //  4,194,304
  float* Psum            = (float*)(ws + 18989568);          //    262,144
  float* Pssq            = (float*)(ws + 19251712);          //    262,144

  pool_quant_kernel<<<21632, 256, 0, stream>>>(s1, s2, s3, alpha, weight,
                                               fusedb, qbf, scales);
  dim3 g(4, 2, 64);
  mfma_gemm_kernel<<<g, 256, 0, stream>>>(qbf, scales, fusedb, bias, ybf,
                                          Psum, Pssq);
  final_kernel<<<2048, 256, 0, stream>>>(ybf, Psum, Pssq, gamma, beta, out);
}

// Round 15
// 93.115 us; speedup vs baseline: 1.0209x; 1.0202x over previous
//
#include <hip/hip_runtime.h>
#include <hip/hip_bf16.h>

#define EPSV 1e-5f

typedef __attribute__((ext_vector_type(8))) short short8v;
typedef __attribute__((ext_vector_type(4))) short short4v;
typedef __attribute__((ext_vector_type(4))) float float4v;

__device__ inline unsigned short f2bf(float x) {
  __hip_bfloat16 h = __float2bfloat16(x);   // RNE
  return *reinterpret_cast<unsigned short*>(&h);
}
__device__ inline float bf2f(unsigned short b) {
  unsigned u = ((unsigned)b) << 16;
  float f;
  __builtin_memcpy(&f, &u, 4);
  return f;
}

// ---- wave-private pool: one wave, one contiguous span of SPAN floats, ------
// ---- NOUT outputs, no barriers (segment is wave-private). ------------------
// Vectorized variant: span base 16B-aligned, SPAN%4==0.
template <int L, int SPAN, int NOUT, int MAXW>
__device__ __forceinline__ void pool_span_vec(
    const float* __restrict__ spanp, int lbase, float wst,
    unsigned short* __restrict__ outp,   // out base for this span's outputs
    float* __restrict__ seg, int lane) {
  constexpr int S4 = SPAN / 4;
  constexpr int NLD = (S4 + 63) / 64;
  constexpr int OPL = NOUT / 64;        // outputs per lane (2 or 4)
  if (lane < MAXW + 3) seg[SPAN + lane] = 0.f;
  const float4v* rp = (const float4v*)spanp;
  #pragma unroll
  for (int j = 0; j < NLD; ++j) {
    int idx = lane + 64 * j;
    if (NLD * 64 == S4 || idx < S4) {
      float4v v = __builtin_nontemporal_load(rp + idx);
      *(float4v*)&seg[idx * 4] = v;
    }
  }
  int sbase = (lbase * L) >> 8;              // exact at span boundaries
  unsigned short res[OPL];
  #pragma unroll
  for (int oo = 0; oo < OPL; ++oo) {
    int l = lbase + lane * OPL + oo;           // global output index
    int start = ((l * L) >> 8) - sbase;
    int end = (((l + 1) * L + 255) >> 8) - sbase;
    int width = end - start;
    float s = 0.f;
    #pragma unroll
    for (int i = 0; i < MAXW; ++i) {
      float v = seg[start + i];
      s += (i < width) ? v : 0.f;
    }
    res[oo] = f2bf(s / (float)width * wst);
  }
  if (OPL == 2) {
    unsigned pk = ((unsigned)res[1] << 16) | res[0];
    *(unsigned*)(outp + lane * 2) = pk;
  } else {
    unsigned pk0 = ((unsigned)res[1] << 16) | res[0];
    unsigned pk1 = ((unsigned)res[3] << 16) | res[2];
    unsigned long long pk = ((unsigned long long)pk1 << 32) | pk0;
    *(unsigned long long*)(outp + lane * 4) = pk;
  }
}

// Scalar-load variant (stage3: rows only 4B-aligned).
template <int L, int SPAN, int NOUT, int MAXW>
__device__ __forceinline__ void pool_span_scalar(
    const float* __restrict__ spanp, int lbase, float wst,
    unsigned short* __restrict__ outp, float* __restrict__ seg, int lane) {
  constexpr int NLD = (SPAN + 63) / 64;
  constexpr int OPL = NOUT / 64;
  if (lane < MAXW + 3) seg[SPAN + lane] = 0.f;
  #pragma unroll
  for (int j = 0; j < NLD; ++j) {
    int idx = lane + 64 * j;
    if (idx < SPAN) seg[idx] = __builtin_nontemporal_load(spanp + idx);
  }
  int sbase = (lbase * L) >> 8;
  unsigned short res[OPL];
  #pragma unroll
  for (int oo = 0; oo < OPL; ++oo) {
    int l = lbase + lane * OPL + oo;
    int start = ((l * L) >> 8) - sbase;
    int end = (((l + 1) * L + 255) >> 8) - sbase;
    int width = end - start;
    float s = 0.f;
    #pragma unroll
    for (int i = 0; i < MAXW; ++i) {
      float v = seg[start + i];
      s += (i < width) ? v : 0.f;
    }
    res[oo] = f2bf(s / (float)width * wst);
  }
  unsigned pk0 = ((unsigned)res[1] << 16) | res[0];
  unsigned pk1 = ((unsigned)res[3] << 16) | res[2];
  unsigned long long pk = ((unsigned long long)pk1 << 32) | pk0;
  *(unsigned long long*)(outp + lane * 4) = pk;
}

// ------------- Kernel 1: barrier-free wave-private pool + quant tail --------
// 4 waves/block, each wave fully independent in its 2524-float LDS segment.
// s1 half-rows: [0,8192) blocks (4 halves each)
// s2 full rows: [8192,10240)   s3 full rows: [10240,11264)
// quant: [11264,11392)
__global__ __launch_bounds__(256) void pool_quant_kernel(
    const float* __restrict__ s1, const float* __restrict__ s2,
    const float* __restrict__ s3, const float* __restrict__ alpha,
    const float* __restrict__ w, unsigned short* __restrict__ fusedb,
    unsigned short* __restrict__ qbf, float* __restrict__ scales) {
  __shared__ float pool_lds[4][2524];   // 40,384 B -> 4 blocks/CU
  int bid = blockIdx.x;
  int t = threadIdx.x;
  int wv = t >> 6, lane = t & 63;

  if (bid >= 11264) {               // ---- quant tail ----
    int o = bid - 11264;            // 0..127
    const float* wr = w + o * 448;
    float m = 0.f;
    for (int c = t; c < 448; c += 256) m = fmaxf(m, fabsf(wr[c]));
    float* sm = pool_lds[0];        // reuse LDS
    for (int off = 32; off; off >>= 1) m = fmaxf(m, __shfl_down(m, off, 64));
    if ((t & 63) == 0) sm[t >> 6] = m;
    __syncthreads();
    m = fmaxf(fmaxf(sm[0], sm[1]), fmaxf(sm[2], sm[3]));
    float scale = fmaxf(m, 1e-8f);  // qp = 1 for 2-bit symmetric
    for (int c = t; c < 448; c += 256) {
      float q = rintf(wr[c] / scale);      // RNE == jnp.round
      q = fminf(fmaxf(q, -2.f), 1.f);
      qbf[o * 448 + c] = f2bf(q);          // q in {-2,-1,0,1}: exact bf16
    }
    if (t == 0) scales[o] = scale;
    return;
  }

  float a0 = alpha[0], a1 = alpha[1], a2 = alpha[2];
  float mx = fmaxf(a0, fmaxf(a1, a2));
  float e0 = expf(a0 - mx), e1 = expf(a1 - mx), e2 = expf(a2 - mx);
  float esum = e0 + e1 + e2;
  float* seg = pool_lds[wv];

  if (bid < 8192) {
    // ---- stage1: L=5000; unit = half-row (2500 floats, 128 outputs) ----
    int u = bid * 4 + wv;           // half-row id, 0..32767
    int rr = u >> 1, h = u & 1;     // row 0..16383, half 0/1
    int b = rr >> 8, c = rr & 255;
    const float* spanp = s1 + ((size_t)b * 256 + c) * 5000 + h * 2500;
    unsigned short* outp = fusedb + ((size_t)b * 448 + c) * 256 + h * 128;
    pool_span_vec<5000, 2500, 128, 21>(spanp, h * 128, e0 / esum, outp, seg, lane);
  } else if (bid < 10240) {
    // ---- stage2: L=2500; unit = full row (2500 floats, 256 outputs) ----
    int u = (bid - 8192) * 4 + wv;  // row id, 0..8191
    int b = u >> 7, c = u & 127;
    const float* spanp = s2 + ((size_t)b * 128 + c) * 2500;
    unsigned short* outp = fusedb + ((size_t)b * 448 + 256 + c) * 256;
    pool_span_vec<2500, 2500, 256, 11>(spanp, 0, e1 / esum, outp, seg, lane);
  } else {
    // ---- stage3: L=625; unit = full row (625 floats, 256 outputs) ----
    int u = (bid - 10240) * 4 + wv; // row id, 0..4095
    int b = u >> 6, c = u & 63;
    const float* spanp = s3 + ((size_t)b * 64 + c) * 625;
    unsigned short* outp = fusedb + ((size_t)b * 448 + 384 + c) * 256;
    pool_span_scalar<625, 625, 256, 4>(spanp, 0, e2 / esum, outp, seg, lane);
  }
}

// ------------- Kernel 2: MFMA GEMM -> bf16 y + BN partials ------------------
__global__ __launch_bounds__(256) void mfma_gemm_kernel(
    const unsigned short* __restrict__ qbf, const float* __restrict__ scales,
    const unsigned short* __restrict__ fusedb, const float* __restrict__ bias,
    unsigned short* __restrict__ ybf, float* __restrict__ Psum,
    float* __restrict__ Pssq) {
  __shared__ __align__(16) unsigned short Asm[64][40];
  __shared__ __align__(16) unsigned Bsm32[16][66];   // [k-pair 0..15][n 0..63]
  int b = blockIdx.z;
  int o0 = blockIdx.y * 64;
  int l0 = blockIdx.x * 64;
  int tid = threadIdx.x;
  int wave = tid >> 6, lane = tid & 63;
  int wm = wave >> 1, wn = wave & 1;
  int lrow = lane & 15, lg = lane >> 4;
  const unsigned short* Fp = fusedb + (size_t)b * 448 * 256;
  float4v acc[2][2];
  #pragma unroll
  for (int i = 0; i < 2; ++i)
    #pragma unroll
    for (int j = 0; j < 2; ++j) acc[i][j] = (float4v){0.f, 0.f, 0.f, 0.f};
  for (int c0 = 0; c0 < 448; c0 += 32) {
    { int r = tid >> 2, k0 = (tid & 3) * 8;
      *(short8v*)&Asm[r][k0] = *(const short8v*)(qbf + (size_t)(o0 + r) * 448 + c0 + k0); }
    { int kp = tid >> 4, n0 = (tid & 15) * 4;
      const unsigned short* g0 = Fp + (size_t)(c0 + 2 * kp) * 256 + l0 + n0;
      short4v v0 = *(const short4v*)g0;
      short4v v1 = *(const short4v*)(g0 + 256);
      #pragma unroll
      for (int j = 0; j < 4; ++j)
        Bsm32[kp][n0 + j] =
            (((unsigned)(unsigned short)v1[j]) << 16) | (unsigned short)v0[j];
    }
    __syncthreads();
    short8v af[2];
    #pragma unroll
    for (int mf = 0; mf < 2; ++mf)
      af[mf] = *(const short8v*)&Asm[wm * 32 + mf * 16 + lrow][lg * 8];
    #pragma unroll
    for (int nf = 0; nf < 2; ++nf) {
      int n = wn * 32 + nf * 16 + lrow;
      int tmp[4];
      #pragma unroll
      for (int jj = 0; jj < 4; ++jj) tmp[jj] = (int)Bsm32[lg * 4 + jj][n];
      short8v bf;
      __builtin_memcpy(&bf, tmp, 16);
      #pragma unroll
      for (int mf = 0; mf < 2; ++mf)
        acc[mf][nf] = __builtin_amdgcn_mfma_f32_16x16x32_bf16(af[mf], bf, acc[mf][nf], 0, 0, 0);
    }
    __syncthreads();
  }
  float sv[2][4], qv[2][4];
  #pragma unroll
  for (int mf = 0; mf < 2; ++mf) {
    #pragma unroll
    for (int reg = 0; reg < 4; ++reg) {
      int r = o0 + wm * 32 + mf * 16 + lg * 4 + reg;
      float sc = scales[r], bv = bias[r];
      float s = 0.f, q = 0.f;
      #pragma unroll
      for (int nf = 0; nf < 2; ++nf) {
        int col = l0 + wn * 32 + nf * 16 + lrow;
        float val = acc[mf][nf][reg] * sc + bv;
        ybf[((size_t)b * 128 + r) * 256 + col] = f2bf(val);
        s += val; q += val * val;              // partials from f32 (pre-round)
      }
      sv[mf][reg] = s; qv[mf][reg] = q;
    }
  }
  #pragma unroll
  for (int mf = 0; mf < 2; ++mf)
    #pragma unroll
    for (int reg = 0; reg < 4; ++reg)
      #pragma unroll
      for (int m = 1; m < 16; m <<= 1) {
        sv[mf][reg] += __shfl_xor(sv[mf][reg], m, 64);
        qv[mf][reg] += __shfl_xor(qv[mf][reg], m, 64);
      }
  if (lrow == 0) {
    int slot = b * 8 + blockIdx.x * 2 + wn;   // 0..511 fixed slot
    #pragma unroll
    for (int mf = 0; mf < 2; ++mf)
      #pragma unroll
      for (int reg = 0; reg < 4; ++reg) {
        int r = o0 + wm * 32 + mf * 16 + lg * 4 + reg;
        Psum[r * 512 + slot] = sv[mf][reg];
        Pssq[r * 512 + slot] = qv[mf][reg];
      }
  }
}

// ------------- Kernel 3: inline stats + BN + ELU + mean over L --------------
__global__ __launch_bounds__(256) void final_kernel(
    const unsigned short* __restrict__ ybf, const float* __restrict__ Psum,
    const float* __restrict__ Pssq, const float* __restrict__ gamma,
    const float* __restrict__ beta, float* __restrict__ out) {
  int w = threadIdx.x >> 6;
  int lane = threadIdx.x & 63;
  int bo = blockIdx.x * 4 + w;     // b*128 + o
  int o = bo & 127;

  float s = 0.f, q = 0.f;
  const float* Pp = Psum + o * 512 + lane * 8;
  const float* Qp = Pssq + o * 512 + lane * 8;
  #pragma unroll
  for (int i = 0; i < 8; ++i) { s += Pp[i]; q += Qp[i]; }
  #pragma unroll
  for (int m = 1; m < 64; m <<= 1) {
    s += __shfl_xor(s, m, 64);
    q += __shfl_xor(q, m, 64);
  }
  float mean = s * (1.f / 16384.f);
  float var = q * (1.f / 16384.f) - mean * mean;
  float rs = rsqrtf(var + EPSV);
  float a = rs * gamma[o];
  float bb = beta[o] - mean * a;

  ushort4 v = *(const ushort4*)(ybf + (size_t)bo * 256 + lane * 4);
  float acc = 0.f;
  #pragma unroll
  for (int j = 0; j < 4; ++j) {
    float e = bf2f((&v.x)[j]);
    float yn = e * a + bb;
    acc += yn > 0.f ? yn : expm1f(yn);
  }
  for (int m = 32; m; m >>= 1) acc += __shfl_down(acc, m, 64);
  if (lane == 0) out[bo] = acc * (1.f / 256.f);
}

extern "C" void kernel_launch(void* const* d_in, const int* in_sizes, int n_in,
                              void* d_out, int out_size, void* d_ws, size_t ws_size,
                              hipStream_t stream) {
  const float* s1     = (const float*)d_in[0];
  const float* s2     = (const float*)d_in[1];
  const float* s3     = (const float*)d_in[2];
  const float* alpha  = (const float*)d_in[3];
  const float* weight = (const float*)d_in[4];
  const float* bias   = (const float*)d_in[5];
  const float* gamma  = (const float*)d_in[6];
  const float* beta   = (const float*)d_in[7];
  float* out = (float*)d_out;

  char* ws = (char*)d_ws;
  unsigned short* fusedb = (unsigned short*)ws;              // 14,680,064
  unsigned short* qbf    = (unsigned short*)(ws + 14680064); //    114,688
  float* scales          = (float*)(ws + 14794752);          //        512
  unsigned short* ybf    = (unsigned short*)(ws + 14795264); //  4,194,304
  float* Psum            = (float*)(ws + 18989568);          //    262,144
  float* Pssq            = (float*)(ws + 19251712);          //    262,144

  pool_quant_kernel<<<11392, 256, 0, stream>>>(s1, s2, s3, alpha, weight,
                                               fusedb, qbf, scales);
  dim3 g(4, 2, 64);
  mfma_gemm_kernel<<<g, 256, 0, stream>>>(qbf, scales, fusedb, bias, ybf,
                                          Psum, Pssq);
  final_kernel<<<2048, 256, 0, stream>>>(ybf, Psum, Pssq, gamma, beta, out);
}